// Round 11
// baseline (236.932 us; speedup 1.0000x reference)
//
#include <hip/hip_runtime.h>
#include <hip/hip_fp16.h>

#define NN 262144
#define NE 4194304
#define NLOGIT 4
#define NHID 16
#define ND 20   // NLOGIT + NHID
#define ND2 40  // 2*ND

#define NBUCK 512          // buckets
#define BSHIFT 9           // bucket = receiver >> BSHIFT
#define RPB 512            // receivers per bucket (NN / NBUCK)
#define SBITS 18           // sender id bits (NN = 2^18)
#define SMASK ((1u << SBITS) - 1)
#define FBLK 1024          // fill blocks (== gather block's thread count)
#define EPB (NE / FBLK)    // 4096 edges per fill block
#define EPT (EPB / 256)    // 16 edges per thread
#define CAP 9728           // per-bucket LDS edge capacity (mean 8192, +17 sigma)

#define MROW 16            // msg row = 16 uint32 = 32 halfs = 64 B (one cache line)
#define AROW 10            // agg row = 10 uint32 = 20 halfs = 40 B

// ---------------------------------------------------------------------------
// Shared-memory union for the fused msg_mlp / bucket_fill kernel.
// ---------------------------------------------------------------------------
struct FillSmem {
    int cnt[NBUCK];
    int boff[NBUCK];
    int lcur[NBUCK];
    int psum[256];
    unsigned int sorted[EPB];
};

// ---------------------------------------------------------------------------
// 4-input-row FMA block: h1[64] += xc.{x,y,z,w} * W[0..3][64].
// Wb is wave-uniform -> scalar-path loads; h1 static-indexed (registers).
// ---------------------------------------------------------------------------
__device__ __forceinline__ void fma4_64(float* h1, const float4 xc, const float* __restrict__ Wb) {
    #pragma unroll
    for (int j = 0; j < 64; j++) {
        float acc = h1[j];
        acc = fmaf(xc.x, Wb[j], acc);
        acc = fmaf(xc.y, Wb[64 + j], acc);
        acc = fmaf(xc.z, Wb[128 + j], acc);
        acc = fmaf(xc.w, Wb[192 + j], acc);
        h1[j] = acc;
    }
}

// L2 (64 -> 32, ReLU) and L3 (32 -> 20) shared tail. All static indexing.
__device__ __forceinline__ void mlp_tail(
    const float* h1, float* o,
    const float* __restrict__ W2, const float* __restrict__ b2,
    const float* __restrict__ W3, const float* __restrict__ b3)
{
    float h2[32];
    #pragma unroll
    for (int j = 0; j < 32; j++) h2[j] = b2[j];
    #pragma unroll
    for (int i = 0; i < 64; i++) {
        const float hi = h1[i];
        #pragma unroll
        for (int j = 0; j < 32; j++) h2[j] = fmaf(hi, W2[i * 32 + j], h2[j]);
    }
    #pragma unroll
    for (int j = 0; j < 32; j++) h2[j] = fmaxf(h2[j], 0.f);

    #pragma unroll
    for (int j = 0; j < ND; j++) o[j] = b3[j];
    #pragma unroll
    for (int i = 0; i < 32; i++) {
        const float hi = h2[i];
        #pragma unroll
        for (int j = 0; j < ND; j++) o[j] = fmaf(hi, W3[i * ND + j], o[j]);
    }
}

// ---------------------------------------------------------------------------
// Fill body (one block = 4096 edges): LDS counting sort by bucket, one
// contiguous coalesced 16 KB write, per-(block,bucket) (off<<16)|cnt to tab.
// ---------------------------------------------------------------------------
__device__ __forceinline__ void fill_body(
    char* smem, const int* __restrict__ senders, const int* __restrict__ receivers,
    unsigned int* __restrict__ bucketed, unsigned int* __restrict__ tab, const int blk)
{
    FillSmem& S = *reinterpret_cast<FillSmem*>(smem);
    const int tid = threadIdx.x;

    S.cnt[tid] = 0; S.cnt[256 + tid] = 0;
    __syncthreads();

    int rr[EPT], ss[EPT];
    const int base = blk * EPB;
    #pragma unroll
    for (int k = 0; k < EPT; k++) {
        rr[k] = receivers[base + k * 256 + tid];
        ss[k] = senders[base + k * 256 + tid];
        atomicAdd(&S.cnt[rr[k] >> BSHIFT], 1);
    }
    __syncthreads();

    const int c0 = S.cnt[2 * tid], c1 = S.cnt[2 * tid + 1];
    S.psum[tid] = c0 + c1;
    __syncthreads();
    #pragma unroll
    for (int off = 1; off < 256; off <<= 1) {
        int t = (tid >= off) ? S.psum[tid - off] : 0;
        __syncthreads();
        S.psum[tid] += t;
        __syncthreads();
    }
    const int ex = S.psum[tid] - (c0 + c1);
    S.boff[2 * tid] = ex;       S.boff[2 * tid + 1] = ex + c0;
    S.lcur[2 * tid] = ex;       S.lcur[2 * tid + 1] = ex + c0;
    __syncthreads();

    tab[(size_t)blk * NBUCK + tid] =
        ((unsigned int)S.boff[tid] << 16) | (unsigned int)S.cnt[tid];
    tab[(size_t)blk * NBUCK + 256 + tid] =
        ((unsigned int)S.boff[256 + tid] << 16) | (unsigned int)S.cnt[256 + tid];

    #pragma unroll
    for (int k = 0; k < EPT; k++) {
        const int b = rr[k] >> BSHIFT;
        const int slot = atomicAdd(&S.lcur[b], 1);
        S.sorted[slot] = (((unsigned int)(rr[k] & (RPB - 1))) << SBITS) | (unsigned int)ss[k];
    }
    __syncthreads();

    const uint4* s4 = reinterpret_cast<const uint4*>(S.sorted);
    uint4* o4 = reinterpret_cast<uint4*>(bucketed + (size_t)blk * EPB);
    #pragma unroll
    for (int k = 0; k < EPB / 4 / 256; k++)
        o4[k * 256 + tid] = s4[k * 256 + tid];
}

// ---------------------------------------------------------------------------
// Msg-MLP body (one block = 256 nodes): scalar-weight MLP + fp16 pack.
// ---------------------------------------------------------------------------
__device__ __forceinline__ void msg_body(
    char* smem, const float* __restrict__ logits, const float* __restrict__ hidden,
    const float* __restrict__ W1, const float* __restrict__ b1,
    const float* __restrict__ W2, const float* __restrict__ b2,
    const float* __restrict__ W3, const float* __restrict__ b3,
    unsigned int* __restrict__ msgh, const int mblk)
{
    float* Ol = reinterpret_cast<float*>(smem);   // 256*ND floats
    const int tid = threadIdx.x;
    const int n = mblk * 256 + tid;

    float h1[64];
    #pragma unroll
    for (int j = 0; j < 64; j++) h1[j] = b1[j];

    {   // logits rows 0..3
        const float4 xc = reinterpret_cast<const float4*>(logits)[n];
        fma4_64(h1, xc, W1);
    }
    #pragma unroll 1
    for (int c = 0; c < 4; c++) {   // hidden rows 4..19
        const float4 xc = reinterpret_cast<const float4*>(hidden)[(size_t)n * 4 + c];
        fma4_64(h1, xc, W1 + (4 + 4 * c) * 64);
    }
    #pragma unroll
    for (int j = 0; j < 64; j++) h1[j] = fmaxf(h1[j], 0.f);

    float o[ND];
    mlp_tail(h1, o, W2, b2, W3, b3);

    #pragma unroll
    for (int k = 0; k < ND; k++) Ol[tid * ND + k] = o[k];
    __syncthreads();

    unsigned int* mo = msgh + (size_t)mblk * 256 * MROW;
    #pragma unroll
    for (int u = 0; u < MROW; u++) {
        const int idx = u * 256 + tid;
        const int nn = idx >> 4, slot = idx & 15;
        const int c2 = slot * 2;
        float v0 = 0.f, v1 = 0.f;
        if (c2 < ND) { v0 = Ol[nn * ND + c2]; v1 = Ol[nn * ND + c2 + 1]; }
        __half2 h = __floats2half2_rn(v0, v1);
        mo[idx] = *reinterpret_cast<unsigned int*>(&h);
    }
}

// ---------------------------------------------------------------------------
// Kernel 1 (fused, interleaved): even blocks run fill, odd blocks run msg
// MLP. Interleaving co-locates memory-bound fill and VALU-bound msg blocks
// on every CU from dispatch start (in-order CP dispatch), so the two hide
// under each other instead of running as two sequential phases.
// ---------------------------------------------------------------------------
__global__ __launch_bounds__(256) void fused_msg_fill_kernel(
    const float* __restrict__ logits, const float* __restrict__ hidden,
    const int* __restrict__ senders, const int* __restrict__ receivers,
    const float* __restrict__ W1, const float* __restrict__ b1,
    const float* __restrict__ W2, const float* __restrict__ b2,
    const float* __restrict__ W3, const float* __restrict__ b3,
    unsigned int* __restrict__ msgh,
    unsigned int* __restrict__ bucketed, unsigned int* __restrict__ tab)
{
    __shared__ __align__(16) char smem[sizeof(FillSmem)];
    if ((blockIdx.x & 1) == 0)
        fill_body(smem, senders, receivers, bucketed, tab, blockIdx.x >> 1);
    else
        msg_body(smem, logits, hidden, W1, b1, W2, b2, W3, b3, msgh,
                 blockIdx.x >> 1);
}

// ---------------------------------------------------------------------------
// Kernel 2: transpose tab [FBLK][NBUCK] -> tabT [NBUCK][FBLK] (LDS-tiled).
// ---------------------------------------------------------------------------
__global__ __launch_bounds__(256) void transpose_tab_kernel(
    const unsigned int* __restrict__ in, unsigned int* __restrict__ out)
{
    __shared__ unsigned int t[32][33];
    const int tx = threadIdx.x & 31;
    const int ty0 = (threadIdx.x >> 5) * 4;
    const int bb = blockIdx.x * 32;   // bucket base
    const int kb = blockIdx.y * 32;   // blk base
    #pragma unroll
    for (int k = 0; k < 4; k++)
        t[ty0 + k][tx] = in[(size_t)(kb + ty0 + k) * NBUCK + bb + tx];
    __syncthreads();
    #pragma unroll
    for (int k = 0; k < 4; k++)
        out[(size_t)(bb + ty0 + k) * FBLK + kb + tx] = t[tx][ty0 + k];
}

// ---------------------------------------------------------------------------
// Kernel 3: fused per-bucket group + gather. One block (1024 thr) per
// bucket. Two-pass grouping; msgh inner loop unrolled x8; fp16 agg output.
// ---------------------------------------------------------------------------
__global__ __launch_bounds__(1024) void bucket_gather_kernel(
    const unsigned int* __restrict__ bucketed,
    const unsigned int* __restrict__ tabT,
    const unsigned int* __restrict__ msgh, unsigned int* __restrict__ aggh)
{
    __shared__ unsigned int elds[CAP];
    __shared__ int dcnt[RPB];
    __shared__ int dcur[RPB];
    const int tid = threadIdx.x;
    const int b = blockIdx.x;

    const unsigned int tv = tabT[(size_t)b * FBLK + tid];
    const int segc = tv & 0xFFFF;
    const unsigned int* seg = bucketed + (size_t)tid * EPB + (tv >> 16);

    if (tid < RPB) dcnt[tid] = 0;
    __syncthreads();
    for (int i = 0; i < segc; i++)
        atomicAdd(&dcnt[seg[i] >> SBITS], 1);
    __syncthreads();
    if (tid < RPB) dcur[tid] = dcnt[tid];
    __syncthreads();
    #pragma unroll
    for (int off = 1; off < RPB; off <<= 1) {
        int t = 0;
        if (tid < RPB && tid >= off) t = dcur[tid - off];
        __syncthreads();
        if (tid < RPB) dcur[tid] += t;
        __syncthreads();
    }
    if (tid < RPB) dcur[tid] -= dcnt[tid];   // exclusive
    __syncthreads();
    for (int i = 0; i < segc; i++) {
        const unsigned int v = seg[i];
        const int slot = atomicAdd(&dcur[v >> SBITS], 1);
        if (slot < CAP) elds[slot] = v & SMASK;
    }
    __syncthreads();

    // per-receiver gather: half-wave groups; lanes 0..9 handle comps 2c,2c+1
    const int hw = tid >> 5;          // 0..31
    const int c = tid & 31;
    const bool act = c < ND / 2;
    for (int rl = hw; rl < RPB; rl += 32) {
        int end = dcur[rl];
        const int cv = dcnt[rl];
        int st = end - cv;
        if (st < 0) st = 0;
        if (end > CAP) end = CAP;
        float a00 = 0.f, a01 = 0.f, a10 = 0.f, a11 = 0.f;
        float a20 = 0.f, a21 = 0.f, a30 = 0.f, a31 = 0.f;
        int i = st;
        for (; i + 7 < end; i += 8) {
            const int s0 = elds[i + 0];
            const int s1 = elds[i + 1];
            const int s2 = elds[i + 2];
            const int s3 = elds[i + 3];
            const int s4 = elds[i + 4];
            const int s5 = elds[i + 5];
            const int s6 = elds[i + 6];
            const int s7 = elds[i + 7];
            if (act) {
                const unsigned int w0 = msgh[s0 * MROW + c];
                const unsigned int w1 = msgh[s1 * MROW + c];
                const unsigned int w2 = msgh[s2 * MROW + c];
                const unsigned int w3 = msgh[s3 * MROW + c];
                const unsigned int w4 = msgh[s4 * MROW + c];
                const unsigned int w5 = msgh[s5 * MROW + c];
                const unsigned int w6 = msgh[s6 * MROW + c];
                const unsigned int w7 = msgh[s7 * MROW + c];
                const float2 f0 = __half22float2(*reinterpret_cast<const __half2*>(&w0));
                const float2 f1 = __half22float2(*reinterpret_cast<const __half2*>(&w1));
                const float2 f2 = __half22float2(*reinterpret_cast<const __half2*>(&w2));
                const float2 f3 = __half22float2(*reinterpret_cast<const __half2*>(&w3));
                const float2 f4 = __half22float2(*reinterpret_cast<const __half2*>(&w4));
                const float2 f5 = __half22float2(*reinterpret_cast<const __half2*>(&w5));
                const float2 f6 = __half22float2(*reinterpret_cast<const __half2*>(&w6));
                const float2 f7 = __half22float2(*reinterpret_cast<const __half2*>(&w7));
                a00 += f0.x + f4.x; a01 += f0.y + f4.y;
                a10 += f1.x + f5.x; a11 += f1.y + f5.y;
                a20 += f2.x + f6.x; a21 += f2.y + f6.y;
                a30 += f3.x + f7.x; a31 += f3.y + f7.y;
            }
        }
        for (; i + 3 < end; i += 4) {
            const int s0 = elds[i + 0];
            const int s1 = elds[i + 1];
            const int s2 = elds[i + 2];
            const int s3 = elds[i + 3];
            if (act) {
                const unsigned int w0 = msgh[s0 * MROW + c];
                const unsigned int w1 = msgh[s1 * MROW + c];
                const unsigned int w2 = msgh[s2 * MROW + c];
                const unsigned int w3 = msgh[s3 * MROW + c];
                const float2 f0 = __half22float2(*reinterpret_cast<const __half2*>(&w0));
                const float2 f1 = __half22float2(*reinterpret_cast<const __half2*>(&w1));
                const float2 f2 = __half22float2(*reinterpret_cast<const __half2*>(&w2));
                const float2 f3 = __half22float2(*reinterpret_cast<const __half2*>(&w3));
                a00 += f0.x; a01 += f0.y;
                a10 += f1.x; a11 += f1.y;
                a20 += f2.x; a21 += f2.y;
                a30 += f3.x; a31 += f3.y;
            }
        }
        for (; i < end; i++) {
            const int s = elds[i];
            if (act) {
                const unsigned int w = msgh[s * MROW + c];
                const float2 f = __half22float2(*reinterpret_cast<const __half2*>(&w));
                a00 += f.x; a01 += f.y;
            }
        }
        if (act) {
            const float rx = (a00 + a10) + (a20 + a30);
            const float ry = (a01 + a11) + (a21 + a31);
            __half2 h = __floats2half2_rn(rx, ry);
            aggh[((size_t)b * RPB + rl) * AROW + c] = *reinterpret_cast<unsigned int*>(&h);
        }
    }
}

// ---------------------------------------------------------------------------
// Kernel 4: node output MLP (40 -> 64 -> 32 -> 20), 1 thread = 1 node.
// agg input is fp16 (AROW u32 per node).
// ---------------------------------------------------------------------------
__global__ __launch_bounds__(256) void node_mlp_kernel(
    const float* __restrict__ logits, const float* __restrict__ hidden,
    const unsigned int* __restrict__ aggh,
    const float* __restrict__ W1, const float* __restrict__ b1,
    const float* __restrict__ W2, const float* __restrict__ b2,
    const float* __restrict__ W3, const float* __restrict__ b3,
    float* __restrict__ out)
{
    const int tid = threadIdx.x;
    const int n = blockIdx.x * 256 + tid;

    float h1[64];
    #pragma unroll
    for (int j = 0; j < 64; j++) h1[j] = b1[j];

    {   // logits rows 0..3
        const float4 xc = reinterpret_cast<const float4*>(logits)[n];
        fma4_64(h1, xc, W1);
    }
    #pragma unroll 1
    for (int c = 0; c < 4; c++) {   // hidden rows 4..19
        const float4 xc = reinterpret_cast<const float4*>(hidden)[(size_t)n * 4 + c];
        fma4_64(h1, xc, W1 + (4 + 4 * c) * 64);
    }
    #pragma unroll 1
    for (int c = 0; c < 5; c++) {   // agg rows 20..39 (fp16 -> fp32)
        const uint2 u = reinterpret_cast<const uint2*>(aggh + (size_t)n * AROW)[c];
        const float2 lo = __half22float2(*reinterpret_cast<const __half2*>(&u.x));
        const float2 hi = __half22float2(*reinterpret_cast<const __half2*>(&u.y));
        const float4 xc = make_float4(lo.x, lo.y, hi.x, hi.y);
        fma4_64(h1, xc, W1 + (ND + 4 * c) * 64);
    }
    #pragma unroll
    for (int j = 0; j < 64; j++) h1[j] = fmaxf(h1[j], 0.f);

    float o[ND];
    mlp_tail(h1, o, W2, b2, W3, b3);

    reinterpret_cast<float4*>(out)[n] = make_float4(o[0], o[1], o[2], o[3]);
    float4* ho = reinterpret_cast<float4*>(out + (size_t)NN * NLOGIT + (size_t)n * NHID);
    #pragma unroll
    for (int k = 0; k < 4; k++)
        ho[k] = make_float4(o[4 + k * 4 + 0], o[4 + k * 4 + 1],
                            o[4 + k * 4 + 2], o[4 + k * 4 + 3]);
}

extern "C" void kernel_launch(void* const* d_in, const int* in_sizes, int n_in,
                              void* d_out, int out_size, void* d_ws, size_t ws_size,
                              hipStream_t stream) {
    const float* logits   = (const float*)d_in[0];
    const float* hidden   = (const float*)d_in[1];
    const int*   senders  = (const int*)d_in[2];
    const int*   receivers= (const int*)d_in[3];
    const float* We1 = (const float*)d_in[4];
    const float* be1 = (const float*)d_in[5];
    const float* We2 = (const float*)d_in[6];
    const float* be2 = (const float*)d_in[7];
    const float* We3 = (const float*)d_in[8];
    const float* be3 = (const float*)d_in[9];
    const float* Wn1 = (const float*)d_in[10];
    const float* bn1 = (const float*)d_in[11];
    const float* Wn2 = (const float*)d_in[12];
    const float* bn2 = (const float*)d_in[13];
    const float* Wn3 = (const float*)d_in[14];
    const float* bn3 = (const float*)d_in[15];
    float* out = (float*)d_out;

    // Workspace layout (~48 MB)
    unsigned int* msgh = (unsigned int*)d_ws;          // NN*MROW u32 (16.8 MB, 64B rows)
    unsigned int* aggh = msgh + (size_t)NN * MROW;     // NN*AROW u32 (10.5 MB, 40B rows)
    unsigned int* bucketed = aggh + (size_t)NN * AROW; // NE u32 (16.8 MB)
    unsigned int* tab  = bucketed + NE;                // FBLK*NBUCK u32 (2 MB)
    unsigned int* tabT = tab + (size_t)FBLK * NBUCK;   // NBUCK*FBLK u32 (2 MB)

    fused_msg_fill_kernel<<<FBLK + NN / 256, 256, 0, stream>>>(
        logits, hidden, senders, receivers,
        We1, be1, We2, be2, We3, be3, msgh, bucketed, tab);
    transpose_tab_kernel<<<dim3(NBUCK / 32, FBLK / 32), 256, 0, stream>>>(tab, tabT);
    bucket_gather_kernel<<<NBUCK, 1024, 0, stream>>>(bucketed, tabT, msgh, aggh);
    node_mlp_kernel<<<NN / 256, 256, 0, stream>>>(
        logits, hidden, aggh, Wn1, bn1, Wn2, bn2, Wn3, bn3, out);
}

// Round 12
// 215.520 us; speedup vs baseline: 1.0994x; 1.0994x over previous
//
#include <hip/hip_runtime.h>
#include <hip/hip_fp16.h>

#define NN 262144
#define NE 4194304
#define NLOGIT 4
#define NHID 16
#define ND 20   // NLOGIT + NHID
#define ND2 40  // 2*ND

#define NBUCK 512          // buckets
#define BSHIFT 9           // bucket = receiver >> BSHIFT
#define RPB 512            // receivers per bucket (NN / NBUCK)
#define SBITS 18           // sender id bits (NN = 2^18)
#define SMASK ((1u << SBITS) - 1)
#define FBLK 1024          // fill blocks (== gather block's thread count)
#define EPB (NE / FBLK)    // 4096 edges per fill block
#define EPT (EPB / 256)    // 16 edges per thread
#define CAP 9728           // per-bucket LDS edge capacity (mean 8192, +17 sigma)

#define MROW 16            // msg row = 16 uint32 = 32 halfs = 64 B (one cache line)
#define AROW 10            // agg row = 10 uint32 = 20 halfs = 40 B

// ---------------------------------------------------------------------------
// Shared-memory union for the fused msg_mlp / bucket_fill kernel.
// ---------------------------------------------------------------------------
struct FillSmem {
    int cnt[NBUCK];
    int boff[NBUCK];
    int lcur[NBUCK];
    int psum[256];
    unsigned int sorted[EPB];
};

// ---------------------------------------------------------------------------
// 4-input-row FMA block: h1[64] += xc.{x,y,z,w} * W[0..3][64].
// Wb is wave-uniform -> scalar-path loads; h1 static-indexed (registers).
// ---------------------------------------------------------------------------
__device__ __forceinline__ void fma4_64(float* h1, const float4 xc, const float* __restrict__ Wb) {
    #pragma unroll
    for (int j = 0; j < 64; j++) {
        float acc = h1[j];
        acc = fmaf(xc.x, Wb[j], acc);
        acc = fmaf(xc.y, Wb[64 + j], acc);
        acc = fmaf(xc.z, Wb[128 + j], acc);
        acc = fmaf(xc.w, Wb[192 + j], acc);
        h1[j] = acc;
    }
}

// L2 (64 -> 32, ReLU) and L3 (32 -> 20) shared tail. All static indexing.
__device__ __forceinline__ void mlp_tail(
    const float* h1, float* o,
    const float* __restrict__ W2, const float* __restrict__ b2,
    const float* __restrict__ W3, const float* __restrict__ b3)
{
    float h2[32];
    #pragma unroll
    for (int j = 0; j < 32; j++) h2[j] = b2[j];
    #pragma unroll
    for (int i = 0; i < 64; i++) {
        const float hi = h1[i];
        #pragma unroll
        for (int j = 0; j < 32; j++) h2[j] = fmaf(hi, W2[i * 32 + j], h2[j]);
    }
    #pragma unroll
    for (int j = 0; j < 32; j++) h2[j] = fmaxf(h2[j], 0.f);

    #pragma unroll
    for (int j = 0; j < ND; j++) o[j] = b3[j];
    #pragma unroll
    for (int i = 0; i < 32; i++) {
        const float hi = h2[i];
        #pragma unroll
        for (int j = 0; j < ND; j++) o[j] = fmaf(hi, W3[i * ND + j], o[j]);
    }
}

// ---------------------------------------------------------------------------
// Fill body (one block = 4096 edges): LDS counting sort by bucket, one
// contiguous coalesced 16 KB write, per-(block,bucket) (off<<16)|cnt to tab.
// ---------------------------------------------------------------------------
__device__ __forceinline__ void fill_body(
    char* smem, const int* __restrict__ senders, const int* __restrict__ receivers,
    unsigned int* __restrict__ bucketed, unsigned int* __restrict__ tab, const int blk)
{
    FillSmem& S = *reinterpret_cast<FillSmem*>(smem);
    const int tid = threadIdx.x;

    S.cnt[tid] = 0; S.cnt[256 + tid] = 0;
    __syncthreads();

    int rr[EPT], ss[EPT];
    const int base = blk * EPB;
    #pragma unroll
    for (int k = 0; k < EPT; k++) {
        rr[k] = receivers[base + k * 256 + tid];
        ss[k] = senders[base + k * 256 + tid];
        atomicAdd(&S.cnt[rr[k] >> BSHIFT], 1);
    }
    __syncthreads();

    const int c0 = S.cnt[2 * tid], c1 = S.cnt[2 * tid + 1];
    S.psum[tid] = c0 + c1;
    __syncthreads();
    #pragma unroll
    for (int off = 1; off < 256; off <<= 1) {
        int t = (tid >= off) ? S.psum[tid - off] : 0;
        __syncthreads();
        S.psum[tid] += t;
        __syncthreads();
    }
    const int ex = S.psum[tid] - (c0 + c1);
    S.boff[2 * tid] = ex;       S.boff[2 * tid + 1] = ex + c0;
    S.lcur[2 * tid] = ex;       S.lcur[2 * tid + 1] = ex + c0;
    __syncthreads();

    tab[(size_t)blk * NBUCK + tid] =
        ((unsigned int)S.boff[tid] << 16) | (unsigned int)S.cnt[tid];
    tab[(size_t)blk * NBUCK + 256 + tid] =
        ((unsigned int)S.boff[256 + tid] << 16) | (unsigned int)S.cnt[256 + tid];

    #pragma unroll
    for (int k = 0; k < EPT; k++) {
        const int b = rr[k] >> BSHIFT;
        const int slot = atomicAdd(&S.lcur[b], 1);
        S.sorted[slot] = (((unsigned int)(rr[k] & (RPB - 1))) << SBITS) | (unsigned int)ss[k];
    }
    __syncthreads();

    const uint4* s4 = reinterpret_cast<const uint4*>(S.sorted);
    uint4* o4 = reinterpret_cast<uint4*>(bucketed + (size_t)blk * EPB);
    #pragma unroll
    for (int k = 0; k < EPB / 4 / 256; k++)
        o4[k * 256 + tid] = s4[k * 256 + tid];
}

// ---------------------------------------------------------------------------
// Msg-MLP body (one block = 256 nodes): scalar-weight MLP + fp16 pack.
// ---------------------------------------------------------------------------
__device__ __forceinline__ void msg_body(
    char* smem, const float* __restrict__ logits, const float* __restrict__ hidden,
    const float* __restrict__ W1, const float* __restrict__ b1,
    const float* __restrict__ W2, const float* __restrict__ b2,
    const float* __restrict__ W3, const float* __restrict__ b3,
    unsigned int* __restrict__ msgh, const int mblk)
{
    float* Ol = reinterpret_cast<float*>(smem);   // 256*ND floats
    const int tid = threadIdx.x;
    const int n = mblk * 256 + tid;

    float h1[64];
    #pragma unroll
    for (int j = 0; j < 64; j++) h1[j] = b1[j];

    {   // logits rows 0..3
        const float4 xc = reinterpret_cast<const float4*>(logits)[n];
        fma4_64(h1, xc, W1);
    }
    #pragma unroll 1
    for (int c = 0; c < 4; c++) {   // hidden rows 4..19
        const float4 xc = reinterpret_cast<const float4*>(hidden)[(size_t)n * 4 + c];
        fma4_64(h1, xc, W1 + (4 + 4 * c) * 64);
    }
    #pragma unroll
    for (int j = 0; j < 64; j++) h1[j] = fmaxf(h1[j], 0.f);

    float o[ND];
    mlp_tail(h1, o, W2, b2, W3, b3);

    #pragma unroll
    for (int k = 0; k < ND; k++) Ol[tid * ND + k] = o[k];
    __syncthreads();

    unsigned int* mo = msgh + (size_t)mblk * 256 * MROW;
    #pragma unroll
    for (int u = 0; u < MROW; u++) {
        const int idx = u * 256 + tid;
        const int nn = idx >> 4, slot = idx & 15;
        const int c2 = slot * 2;
        float v0 = 0.f, v1 = 0.f;
        if (c2 < ND) { v0 = Ol[nn * ND + c2]; v1 = Ol[nn * ND + c2 + 1]; }
        __half2 h = __floats2half2_rn(v0, v1);
        mo[idx] = *reinterpret_cast<unsigned int*>(&h);
    }
}

// ---------------------------------------------------------------------------
// Kernel 1 (fused): blocks 0..FBLK-1 run fill, blocks FBLK.. run msg MLP.
// (Fill-first ordering measured faster than even/odd interleave: 217 vs 237
// µs total — interleave put ~3 fill blocks on every CU simultaneously and
// their LDS-atomic/write bursts contended chip-wide.)
// ---------------------------------------------------------------------------
__global__ __launch_bounds__(256) void fused_msg_fill_kernel(
    const float* __restrict__ logits, const float* __restrict__ hidden,
    const int* __restrict__ senders, const int* __restrict__ receivers,
    const float* __restrict__ W1, const float* __restrict__ b1,
    const float* __restrict__ W2, const float* __restrict__ b2,
    const float* __restrict__ W3, const float* __restrict__ b3,
    unsigned int* __restrict__ msgh,
    unsigned int* __restrict__ bucketed, unsigned int* __restrict__ tab)
{
    __shared__ __align__(16) char smem[sizeof(FillSmem)];
    if (blockIdx.x < FBLK)
        fill_body(smem, senders, receivers, bucketed, tab, blockIdx.x);
    else
        msg_body(smem, logits, hidden, W1, b1, W2, b2, W3, b3, msgh,
                 blockIdx.x - FBLK);
}

// ---------------------------------------------------------------------------
// Kernel 2: transpose tab [FBLK][NBUCK] -> tabT [NBUCK][FBLK] (LDS-tiled).
// ---------------------------------------------------------------------------
__global__ __launch_bounds__(256) void transpose_tab_kernel(
    const unsigned int* __restrict__ in, unsigned int* __restrict__ out)
{
    __shared__ unsigned int t[32][33];
    const int tx = threadIdx.x & 31;
    const int ty0 = (threadIdx.x >> 5) * 4;
    const int bb = blockIdx.x * 32;   // bucket base
    const int kb = blockIdx.y * 32;   // blk base
    #pragma unroll
    for (int k = 0; k < 4; k++)
        t[ty0 + k][tx] = in[(size_t)(kb + ty0 + k) * NBUCK + bb + tx];
    __syncthreads();
    #pragma unroll
    for (int k = 0; k < 4; k++)
        out[(size_t)(bb + ty0 + k) * FBLK + kb + tx] = t[tx][ty0 + k];
}

// ---------------------------------------------------------------------------
// Kernel 3: fused per-bucket group + gather. One block (1024 thr) per
// bucket. Two-pass grouping; msgh inner loop unrolled x8; fp16 agg output.
// ---------------------------------------------------------------------------
__global__ __launch_bounds__(1024) void bucket_gather_kernel(
    const unsigned int* __restrict__ bucketed,
    const unsigned int* __restrict__ tabT,
    const unsigned int* __restrict__ msgh, unsigned int* __restrict__ aggh)
{
    __shared__ unsigned int elds[CAP];
    __shared__ int dcnt[RPB];
    __shared__ int dcur[RPB];
    const int tid = threadIdx.x;
    const int b = blockIdx.x;

    const unsigned int tv = tabT[(size_t)b * FBLK + tid];
    const int segc = tv & 0xFFFF;
    const unsigned int* seg = bucketed + (size_t)tid * EPB + (tv >> 16);

    if (tid < RPB) dcnt[tid] = 0;
    __syncthreads();
    for (int i = 0; i < segc; i++)
        atomicAdd(&dcnt[seg[i] >> SBITS], 1);
    __syncthreads();
    if (tid < RPB) dcur[tid] = dcnt[tid];
    __syncthreads();
    #pragma unroll
    for (int off = 1; off < RPB; off <<= 1) {
        int t = 0;
        if (tid < RPB && tid >= off) t = dcur[tid - off];
        __syncthreads();
        if (tid < RPB) dcur[tid] += t;
        __syncthreads();
    }
    if (tid < RPB) dcur[tid] -= dcnt[tid];   // exclusive
    __syncthreads();
    for (int i = 0; i < segc; i++) {
        const unsigned int v = seg[i];
        const int slot = atomicAdd(&dcur[v >> SBITS], 1);
        if (slot < CAP) elds[slot] = v & SMASK;
    }
    __syncthreads();

    // per-receiver gather: half-wave groups; lanes 0..9 handle comps 2c,2c+1
    const int hw = tid >> 5;          // 0..31
    const int c = tid & 31;
    const bool act = c < ND / 2;
    for (int rl = hw; rl < RPB; rl += 32) {
        int end = dcur[rl];
        const int cv = dcnt[rl];
        int st = end - cv;
        if (st < 0) st = 0;
        if (end > CAP) end = CAP;
        float a00 = 0.f, a01 = 0.f, a10 = 0.f, a11 = 0.f;
        float a20 = 0.f, a21 = 0.f, a30 = 0.f, a31 = 0.f;
        int i = st;
        for (; i + 7 < end; i += 8) {
            const int s0 = elds[i + 0];
            const int s1 = elds[i + 1];
            const int s2 = elds[i + 2];
            const int s3 = elds[i + 3];
            const int s4 = elds[i + 4];
            const int s5 = elds[i + 5];
            const int s6 = elds[i + 6];
            const int s7 = elds[i + 7];
            if (act) {
                const unsigned int w0 = msgh[s0 * MROW + c];
                const unsigned int w1 = msgh[s1 * MROW + c];
                const unsigned int w2 = msgh[s2 * MROW + c];
                const unsigned int w3 = msgh[s3 * MROW + c];
                const unsigned int w4 = msgh[s4 * MROW + c];
                const unsigned int w5 = msgh[s5 * MROW + c];
                const unsigned int w6 = msgh[s6 * MROW + c];
                const unsigned int w7 = msgh[s7 * MROW + c];
                const float2 f0 = __half22float2(*reinterpret_cast<const __half2*>(&w0));
                const float2 f1 = __half22float2(*reinterpret_cast<const __half2*>(&w1));
                const float2 f2 = __half22float2(*reinterpret_cast<const __half2*>(&w2));
                const float2 f3 = __half22float2(*reinterpret_cast<const __half2*>(&w3));
                const float2 f4 = __half22float2(*reinterpret_cast<const __half2*>(&w4));
                const float2 f5 = __half22float2(*reinterpret_cast<const __half2*>(&w5));
                const float2 f6 = __half22float2(*reinterpret_cast<const __half2*>(&w6));
                const float2 f7 = __half22float2(*reinterpret_cast<const __half2*>(&w7));
                a00 += f0.x + f4.x; a01 += f0.y + f4.y;
                a10 += f1.x + f5.x; a11 += f1.y + f5.y;
                a20 += f2.x + f6.x; a21 += f2.y + f6.y;
                a30 += f3.x + f7.x; a31 += f3.y + f7.y;
            }
        }
        for (; i + 3 < end; i += 4) {
            const int s0 = elds[i + 0];
            const int s1 = elds[i + 1];
            const int s2 = elds[i + 2];
            const int s3 = elds[i + 3];
            if (act) {
                const unsigned int w0 = msgh[s0 * MROW + c];
                const unsigned int w1 = msgh[s1 * MROW + c];
                const unsigned int w2 = msgh[s2 * MROW + c];
                const unsigned int w3 = msgh[s3 * MROW + c];
                const float2 f0 = __half22float2(*reinterpret_cast<const __half2*>(&w0));
                const float2 f1 = __half22float2(*reinterpret_cast<const __half2*>(&w1));
                const float2 f2 = __half22float2(*reinterpret_cast<const __half2*>(&w2));
                const float2 f3 = __half22float2(*reinterpret_cast<const __half2*>(&w3));
                a00 += f0.x; a01 += f0.y;
                a10 += f1.x; a11 += f1.y;
                a20 += f2.x; a21 += f2.y;
                a30 += f3.x; a31 += f3.y;
            }
        }
        for (; i < end; i++) {
            const int s = elds[i];
            if (act) {
                const unsigned int w = msgh[s * MROW + c];
                const float2 f = __half22float2(*reinterpret_cast<const __half2*>(&w));
                a00 += f.x; a01 += f.y;
            }
        }
        if (act) {
            const float rx = (a00 + a10) + (a20 + a30);
            const float ry = (a01 + a11) + (a21 + a31);
            __half2 h = __floats2half2_rn(rx, ry);
            aggh[((size_t)b * RPB + rl) * AROW + c] = *reinterpret_cast<unsigned int*>(&h);
        }
    }
}

// ---------------------------------------------------------------------------
// Kernel 4: node output MLP (40 -> 64 -> 32 -> 20), 1 thread = 1 node.
// agg input is fp16 (AROW u32 per node).
// ---------------------------------------------------------------------------
__global__ __launch_bounds__(256) void node_mlp_kernel(
    const float* __restrict__ logits, const float* __restrict__ hidden,
    const unsigned int* __restrict__ aggh,
    const float* __restrict__ W1, const float* __restrict__ b1,
    const float* __restrict__ W2, const float* __restrict__ b2,
    const float* __restrict__ W3, const float* __restrict__ b3,
    float* __restrict__ out)
{
    const int tid = threadIdx.x;
    const int n = blockIdx.x * 256 + tid;

    float h1[64];
    #pragma unroll
    for (int j = 0; j < 64; j++) h1[j] = b1[j];

    {   // logits rows 0..3
        const float4 xc = reinterpret_cast<const float4*>(logits)[n];
        fma4_64(h1, xc, W1);
    }
    #pragma unroll 1
    for (int c = 0; c < 4; c++) {   // hidden rows 4..19
        const float4 xc = reinterpret_cast<const float4*>(hidden)[(size_t)n * 4 + c];
        fma4_64(h1, xc, W1 + (4 + 4 * c) * 64);
    }
    #pragma unroll 1
    for (int c = 0; c < 5; c++) {   // agg rows 20..39 (fp16 -> fp32)
        const uint2 u = reinterpret_cast<const uint2*>(aggh + (size_t)n * AROW)[c];
        const float2 lo = __half22float2(*reinterpret_cast<const __half2*>(&u.x));
        const float2 hi = __half22float2(*reinterpret_cast<const __half2*>(&u.y));
        const float4 xc = make_float4(lo.x, lo.y, hi.x, hi.y);
        fma4_64(h1, xc, W1 + (ND + 4 * c) * 64);
    }
    #pragma unroll
    for (int j = 0; j < 64; j++) h1[j] = fmaxf(h1[j], 0.f);

    float o[ND];
    mlp_tail(h1, o, W2, b2, W3, b3);

    reinterpret_cast<float4*>(out)[n] = make_float4(o[0], o[1], o[2], o[3]);
    float4* ho = reinterpret_cast<float4*>(out + (size_t)NN * NLOGIT + (size_t)n * NHID);
    #pragma unroll
    for (int k = 0; k < 4; k++)
        ho[k] = make_float4(o[4 + k * 4 + 0], o[4 + k * 4 + 1],
                            o[4 + k * 4 + 2], o[4 + k * 4 + 3]);
}

extern "C" void kernel_launch(void* const* d_in, const int* in_sizes, int n_in,
                              void* d_out, int out_size, void* d_ws, size_t ws_size,
                              hipStream_t stream) {
    const float* logits   = (const float*)d_in[0];
    const float* hidden   = (const float*)d_in[1];
    const int*   senders  = (const int*)d_in[2];
    const int*   receivers= (const int*)d_in[3];
    const float* We1 = (const float*)d_in[4];
    const float* be1 = (const float*)d_in[5];
    const float* We2 = (const float*)d_in[6];
    const float* be2 = (const float*)d_in[7];
    const float* We3 = (const float*)d_in[8];
    const float* be3 = (const float*)d_in[9];
    const float* Wn1 = (const float*)d_in[10];
    const float* bn1 = (const float*)d_in[11];
    const float* Wn2 = (const float*)d_in[12];
    const float* bn2 = (const float*)d_in[13];
    const float* Wn3 = (const float*)d_in[14];
    const float* bn3 = (const float*)d_in[15];
    float* out = (float*)d_out;

    // Workspace layout (~48 MB)
    unsigned int* msgh = (unsigned int*)d_ws;          // NN*MROW u32 (16.8 MB, 64B rows)
    unsigned int* aggh = msgh + (size_t)NN * MROW;     // NN*AROW u32 (10.5 MB, 40B rows)
    unsigned int* bucketed = aggh + (size_t)NN * AROW; // NE u32 (16.8 MB)
    unsigned int* tab  = bucketed + NE;                // FBLK*NBUCK u32 (2 MB)
    unsigned int* tabT = tab + (size_t)FBLK * NBUCK;   // NBUCK*FBLK u32 (2 MB)

    fused_msg_fill_kernel<<<FBLK + NN / 256, 256, 0, stream>>>(
        logits, hidden, senders, receivers,
        We1, be1, We2, be2, We3, be3, msgh, bucketed, tab);
    transpose_tab_kernel<<<dim3(NBUCK / 32, FBLK / 32), 256, 0, stream>>>(tab, tabT);
    bucket_gather_kernel<<<NBUCK, 1024, 0, stream>>>(bucketed, tabT, msgh, aggh);
    node_mlp_kernel<<<NN / 256, 256, 0, stream>>>(
        logits, hidden, aggh, Wn1, bn1, Wn2, bn2, Wn3, bn3, out);
}